// Round 9
// baseline (1051.234 us; speedup 1.0000x reference)
//
#include <hip/hip_runtime.h>
#include <hip/hip_bf16.h>
#include <math.h>

#define N_NODES 80000
#define N_EDGES 1280000
#define NBKT 8
#define BKT_DIV 10000               // bucket = dst / 10000  -> 0..7
#define BKT_CAP 165000              // mean 160000, sigma ~374; huge margin
#define EPB 1280                    // edges per k_part block (grid 1000)

typedef __hip_bfloat16 bf16;

__device__ __forceinline__ float leaky(float x) { return x >= 0.f ? x : 0.01f * x; }

// ---------------- setup kernels ----------------

__global__ void k_zero(int* deg, float* bnsums, int* tails) {
    int i = blockIdx.x * blockDim.x + threadIdx.x;
    if (i < N_NODES) deg[i] = 0;
    if (i < 384) bnsums[i] = 0.f;
    if (i < NBKT) tails[i] = 0;
}

// pass 1: bin raw (src,dst) pairs by dst-range. Block bulk-reserves per-bucket
// regions; NO per-edge weights anywhere (factorized out: w = dinv_s*dinv_d).
__global__ void __launch_bounds__(256)
k_part(const int* __restrict__ ei, int2* __restrict__ pairs,
       int* __restrict__ tails) {
    __shared__ int cnt[NBKT], off[NBKT];
    int t = threadIdx.x;
    if (t < NBKT) cnt[t] = 0;
    __syncthreads();
    int base = blockIdx.x * EPB;
    int2 loc[5];
#pragma unroll
    for (int u = 0; u < 5; ++u) {
        int e = base + u * 256 + t;
        int s = ei[e], d = ei[N_EDGES + e];
        loc[u] = make_int2(s, d);
        atomicAdd(&cnt[d / BKT_DIV], 1);
    }
    __syncthreads();
    if (t < NBKT) off[t] = atomicAdd(&tails[t], cnt[t]);
    __syncthreads();
#pragma unroll
    for (int u = 0; u < 5; ++u) {
        int b = loc[u].y / BKT_DIV;
        int pos = atomicAdd(&off[b], 1);
        pairs[(size_t)b * BKT_CAP + pos] = loc[u];
    }
}

// deg counting with XCD-local atomics (blockIdx&7 == bucket).
__global__ void __launch_bounds__(256)
k_deg_bkt(const int2* __restrict__ pairs, const int* __restrict__ tails,
          int* __restrict__ deg) {
    int bucket = blockIdx.x & 7;
    int jb = blockIdx.x >> 3;
    int nb = gridDim.x >> 3;
    int cnt = tails[bucket];
    const int2* lst = pairs + (size_t)bucket * BKT_CAP;
    for (int i = jb * 256 + threadIdx.x; i < cnt; i += nb * 256)
        atomicAdd(&deg[lst[i].y], 1);
}

__global__ void k_dinv(const int* __restrict__ deg, float* __restrict__ dinv) {
    int i = blockIdx.x * blockDim.x + threadIdx.x;
    if (i < N_NODES) dinv[i] = rsqrtf((float)deg[i] + 2.0f);  // + self-loop weight 2
}

// h0 = x @ W0; hs = bf16(dinv*h0) (pre-scaled gather rows); yraw = 2*dinv*h0
__global__ void k_h0y(const float* __restrict__ x, const float* __restrict__ W0,
                      const float* __restrict__ dinv,
                      bf16* __restrict__ hs, float* __restrict__ yraw) {
    int tid = blockIdx.x * blockDim.x + threadIdx.x;
    if (tid < N_NODES * 64) {
        int v = tid >> 6, c = tid & 63;
        float x0 = x[v * 3], x1 = x[v * 3 + 1], x2 = x[v * 3 + 2];
        float h = x0 * W0[c] + x1 * W0[64 + c] + x2 * W0[128 + c];
        float dv = dinv[v];
        hs[tid] = __float2bfloat16(dv * h);
        yraw[tid] = 2.f * dv * h;
    }
}

// ---------------- per-stage kernels ----------------

// bucket-pinned edge-stream aggregation: wave = 8-edge batches from its
// bucket's pair list. Gathers hs[src] (pre-scaled), fire-and-forget vector
// atomicAdd into yraw[dst] — dst confined to the bucket's 2.56 MB slice
// (XCD-local L2 atomics via blockIdx&7 pinning).
__global__ void __launch_bounds__(256)
k_agg_b(const bf16* __restrict__ hs, const int2* __restrict__ pairs,
        const int* __restrict__ tails, float* __restrict__ yraw) {
    int lane = threadIdx.x & 63;
    int bucket = blockIdx.x & 7;
    int wv = ((blockIdx.x >> 3) << 2) + (threadIdx.x >> 6);
    int nwv = (gridDim.x >> 3) << 2;
    int cnt = tails[bucket];
    const int2* lst = pairs + (size_t)bucket * BKT_CAP;
    for (int e0 = wv * 8; e0 < cnt; e0 += nwv * 8) {
        int m = cnt - e0;  // wave-uniform
        if (m >= 8) {
            int2 c[8];
#pragma unroll
            for (int u = 0; u < 8; ++u) c[u] = lst[e0 + u];
            float pv[8];
#pragma unroll
            for (int u = 0; u < 8; ++u)
                pv[u] = __bfloat162float(hs[(size_t)c[u].x * 64 + lane]);
#pragma unroll
            for (int u = 0; u < 8; ++u)
                atomicAdd(&yraw[(size_t)c[u].y * 64 + lane], pv[u]);
        } else {
            for (int u = 0; u < m; ++u) {
                int2 c = lst[e0 + u];
                float pv = __bfloat162float(hs[(size_t)c.x * 64 + lane]);
                atomicAdd(&yraw[(size_t)c.y * 64 + lane], pv);
            }
        }
    }
}

// per-channel sum/sumsq of y_final = dinv[v]*yraw + bias[c]
__global__ void __launch_bounds__(256)
k_bnstats(const float* __restrict__ yraw, const float* __restrict__ dinv,
          const float* __restrict__ bias, float* __restrict__ bnsum) {
    int tid = blockIdx.x * blockDim.x + threadIdx.x;
    int stride = gridDim.x * blockDim.x;  // multiple of 64
    float bc = bias[tid & 63];
    float bs = 0.f, bss = 0.f;
    for (size_t i = tid; i < (size_t)N_NODES * 64; i += stride) {
        float yf = dinv[i >> 6] * yraw[i] + bc;
        bs += yf;
        bss += yf * yf;
    }
    __shared__ float s1[256], s2[256];
    s1[threadIdx.x] = bs;
    s2[threadIdx.x] = bss;
    __syncthreads();
    if (threadIdx.x < 64) {
        float t1 = s1[threadIdx.x] + s1[threadIdx.x + 64] + s1[threadIdx.x + 128] + s1[threadIdx.x + 192];
        float t2 = s2[threadIdx.x] + s2[threadIdx.x + 64] + s2[threadIdx.x + 128] + s2[threadIdx.x + 192];
        atomicAdd(&bnsum[threadIdx.x], t1);
        atomicAdd(&bnsum[64 + threadIdx.x], t2);
    }
}

// BN + maxpool + leaky + (a@lw.T+lb) + leaky + second matmul, register-tiled.
// y_final = dinv[node]*yraw + bias[c] folded into phase-1 scale/shift.
// MODE 0: phase3 = o @ Wn (64x64) -> hs_next = bf16(dinv*hn), yraw_next = 2*dinv*hn.
// MODE 1: phase3 = o @ Wn (64x3)  -> hs3 = float4(dinv*h3), y3raw = float4(2*dinv*h3).
template <int P, int MODE>
__global__ void __launch_bounds__(128)
k_post64(const float* __restrict__ yraw, const float* __restrict__ dinv,
         const float* __restrict__ bias, const float* __restrict__ bnsum,
         const float* __restrict__ g, const float* __restrict__ bb,
         const float* __restrict__ lw, const float* __restrict__ lb,
         const float* __restrict__ Wn, bf16* __restrict__ hsout,
         float* __restrict__ yrawnext,
         float4* __restrict__ hs3, float4* __restrict__ y3raw) {
    __shared__ float s_aT[2][64 * 36];  // per-wave activation tile (transposed), reused as oT
    __shared__ float s_lwT[64 * 64];    // lw transposed: [k][c]
    __shared__ float s_Wn[MODE == 0 ? 64 * 64 : 64 * 3];
    int t = threadIdx.x;
    int w = t >> 6, lane = t & 63;
    for (int k0 = t; k0 < 4096; k0 += 128) {
        int kk = k0 >> 6, cc = k0 & 63;
        s_lwT[kk * 64 + cc] = lw[cc * 64 + kk];
        if (MODE == 0) s_Wn[k0] = Wn[k0];
    }
    if (MODE == 1) {
        for (int i = t; i < 64 * 3; i += 128) s_Wn[i] = Wn[i];
    }
    float inv_n = 1.0f / (float)N_NODES;
    float mean = bnsum[lane] * inv_n;
    float var = fmaxf(bnsum[64 + lane] * inv_n - mean * mean, 0.f);
    float sc = g[lane] * rsqrtf(var + 1e-5f);
    float sh = bb[lane] - mean * sc;
    float shb = fmaf(sc, bias[lane], sh);  // folds GCN bias into BN shift
    int c0 = (lane >> 3) * 8, n0 = (lane & 7) * 4;
    float lbv[8];
#pragma unroll
    for (int i = 0; i < 8; ++i) lbv[i] = lb[c0 + i];
    float* aT = s_aT[w];

    for (int tile = blockIdx.x; tile < N_NODES / 64; tile += gridDim.x) {
        int nbase = tile * 64 + w * 32;
        __syncthreads();  // also covers initial weight-fill -> first use
#pragma unroll 4
        for (int i = 0; i < 32; ++i) {
            float dvv = dinv[nbase + i];
            float z = fmaf(sc * dvv, yraw[(size_t)(nbase + i) * 64 + lane], shb);
            float m = z;
#pragma unroll
            for (int d = 1; d <= P; ++d) {
                float up = __shfl(z, lane + d);
                float dn = __shfl(z, lane - d);
                m = fmaxf(m, (lane + d < 64) ? up : -INFINITY);
                m = fmaxf(m, (lane - d >= 0) ? dn : -INFINITY);
            }
            aT[lane * 36 + i] = leaky(m);
        }
        __syncthreads();
        // phase 2: o = leaky(a @ lw.T + lb)
        float acc[4][8];
#pragma unroll
        for (int nn = 0; nn < 4; ++nn)
#pragma unroll
            for (int i = 0; i < 8; ++i) acc[nn][i] = lbv[i];
#pragma unroll 8
        for (int k = 0; k < 64; ++k) {
            float4 av = *(const float4*)&aT[k * 36 + n0];
            float4 w0 = *(const float4*)&s_lwT[k * 64 + c0];
            float4 w1 = *(const float4*)&s_lwT[k * 64 + c0 + 4];
            float a4[4] = {av.x, av.y, av.z, av.w};
            float wv[8] = {w0.x, w0.y, w0.z, w0.w, w1.x, w1.y, w1.z, w1.w};
#pragma unroll
            for (int nn = 0; nn < 4; ++nn)
#pragma unroll
                for (int i = 0; i < 8; ++i) acc[nn][i] = fmaf(a4[nn], wv[i], acc[nn][i]);
        }
#pragma unroll
        for (int nn = 0; nn < 4; ++nn)
#pragma unroll
            for (int i = 0; i < 8; ++i) acc[nn][i] = leaky(acc[nn][i]);

        // write oT (aliases aT; same-wave LDS program order is safe)
#pragma unroll
        for (int i = 0; i < 8; ++i) {
            float4 ov = make_float4(acc[0][i], acc[1][i], acc[2][i], acc[3][i]);
            *(float4*)&aT[(c0 + i) * 36 + n0] = ov;
        }
        if (MODE == 0) {
            float acc2[4][8];
#pragma unroll
            for (int nn = 0; nn < 4; ++nn)
#pragma unroll
                for (int i = 0; i < 8; ++i) acc2[nn][i] = 0.f;
#pragma unroll 8
            for (int k = 0; k < 64; ++k) {
                float4 av = *(const float4*)&aT[k * 36 + n0];
                float4 w0 = *(const float4*)&s_Wn[k * 64 + c0];
                float4 w1 = *(const float4*)&s_Wn[k * 64 + c0 + 4];
                float a4[4] = {av.x, av.y, av.z, av.w};
                float wv[8] = {w0.x, w0.y, w0.z, w0.w, w1.x, w1.y, w1.z, w1.w};
#pragma unroll
                for (int nn = 0; nn < 4; ++nn)
#pragma unroll
                    for (int i = 0; i < 8; ++i) acc2[nn][i] = fmaf(a4[nn], wv[i], acc2[nn][i]);
            }
#pragma unroll
            for (int nn = 0; nn < 4; ++nn) {
                int node = nbase + n0 + nn;
                float dv = dinv[node];
                bf16 pk[8];
                float yn[8];
#pragma unroll
                for (int i = 0; i < 8; ++i) {
                    pk[i] = __float2bfloat16(dv * acc2[nn][i]);
                    yn[i] = 2.f * dv * acc2[nn][i];
                }
                *(uint4*)&hsout[(size_t)node * 64 + c0] = *(uint4*)pk;
                *(float4*)&yrawnext[(size_t)node * 64 + c0] = make_float4(yn[0], yn[1], yn[2], yn[3]);
                *(float4*)&yrawnext[(size_t)node * 64 + c0 + 4] = make_float4(yn[4], yn[5], yn[6], yn[7]);
            }
        } else {
            // proj fused: h3 = o @ w2 (64x3); 8 lanes duplicate, c0==0 writes
            float acc3[4][3];
#pragma unroll
            for (int nn = 0; nn < 4; ++nn)
#pragma unroll
                for (int j = 0; j < 3; ++j) acc3[nn][j] = 0.f;
#pragma unroll 8
            for (int k = 0; k < 64; ++k) {
                float4 av = *(const float4*)&aT[k * 36 + n0];
                float a4[4] = {av.x, av.y, av.z, av.w};
                float w0 = s_Wn[k * 3 + 0], w1 = s_Wn[k * 3 + 1], w2v = s_Wn[k * 3 + 2];
#pragma unroll
                for (int nn = 0; nn < 4; ++nn) {
                    acc3[nn][0] = fmaf(a4[nn], w0, acc3[nn][0]);
                    acc3[nn][1] = fmaf(a4[nn], w1, acc3[nn][1]);
                    acc3[nn][2] = fmaf(a4[nn], w2v, acc3[nn][2]);
                }
            }
            if (c0 == 0) {
#pragma unroll
                for (int nn = 0; nn < 4; ++nn) {
                    int node = nbase + n0 + nn;
                    float dv = dinv[node];
                    hs3[node] = make_float4(dv * acc3[nn][0], dv * acc3[nn][1], dv * acc3[nn][2], 0.f);
                    y3raw[node] = make_float4(2.f * dv * acc3[nn][0], 2.f * dv * acc3[nn][1],
                                              2.f * dv * acc3[nn][2], 0.f);
                }
            }
        }
    }
}

// stage-2 aggregation: thread-per-edge, bucket-pinned XCD-local atomics.
__global__ void __launch_bounds__(256)
k_agg3_b(const float4* __restrict__ hs3, const int2* __restrict__ pairs,
         const int* __restrict__ tails, float* __restrict__ y3raw) {
    int bucket = blockIdx.x & 7;
    int idx0 = (blockIdx.x >> 3) * 256 + threadIdx.x;
    int stride = (gridDim.x >> 3) * 256;
    int cnt = tails[bucket];
    const int2* lst = pairs + (size_t)bucket * BKT_CAP;
    for (int i = idx0; i < cnt; i += stride) {
        int2 pr = lst[i];
        float4 h = hs3[pr.x];
        atomicAdd(&y3raw[pr.y * 4 + 0], h.x);
        atomicAdd(&y3raw[pr.y * 4 + 1], h.y);
        atomicAdd(&y3raw[pr.y * 4 + 2], h.z);
    }
}

// stage-2 BN stats over y_final = dinv*y3raw + b2
__global__ void __launch_bounds__(256)
k_bnstats3(const float* __restrict__ y3raw, const float* __restrict__ dinv,
           const float* __restrict__ b2, float* __restrict__ bnsum) {
    int v = blockIdx.x * blockDim.x + threadIdx.x;
    float y0 = 0.f, y1 = 0.f, y2 = 0.f;
    if (v < N_NODES) {
        float dv = dinv[v];
        y0 = dv * y3raw[v * 4 + 0] + b2[0];
        y1 = dv * y3raw[v * 4 + 1] + b2[1];
        y2 = dv * y3raw[v * 4 + 2] + b2[2];
    }
    __shared__ float sm[256];
    float vals[6] = {y0, y1, y2, y0 * y0, y1 * y1, y2 * y2};
    for (int c = 0; c < 6; ++c) {
        sm[threadIdx.x] = (v < N_NODES) ? vals[c] : 0.f;
        __syncthreads();
        for (int off = 128; off > 0; off >>= 1) {
            if (threadIdx.x < off) sm[threadIdx.x] += sm[threadIdx.x + off];
            __syncthreads();
        }
        if (threadIdx.x == 0) atomicAdd(&bnsum[c], sm[0]);
        __syncthreads();
    }
}

// final stage post: BN + pool(3,1) + leaky + 3x3 linear + leaky
__global__ void k_post3(const float* __restrict__ y3raw, const float* __restrict__ dinv,
                        const float* __restrict__ b2, const float* __restrict__ bnsum,
                        const float* __restrict__ g, const float* __restrict__ bb,
                        const float* __restrict__ lw, const float* __restrict__ lb,
                        float* __restrict__ out) {
    int v = blockIdx.x * blockDim.x + threadIdx.x;
    if (v >= N_NODES) return;
    float inv_n = 1.0f / (float)N_NODES;
    float sc[3], sh[3];
#pragma unroll
    for (int c = 0; c < 3; ++c) {
        float mean = bnsum[c] * inv_n;
        float var = fmaxf(bnsum[3 + c] * inv_n - mean * mean, 0.f);
        sc[c] = g[c] * rsqrtf(var + 1e-5f);
        sh[c] = bb[c] - mean * sc[c];
    }
    float dv = dinv[v];
    float z0 = fmaf(dv * y3raw[v * 4 + 0] + b2[0], sc[0], sh[0]);
    float z1 = fmaf(dv * y3raw[v * 4 + 1] + b2[1], sc[1], sh[1]);
    float z2 = fmaf(dv * y3raw[v * 4 + 2] + b2[2], sc[2], sh[2]);
    float p0 = fmaxf(z0, z1);
    float p1 = fmaxf(p0, z2);
    float p2 = fmaxf(z1, z2);
    float a0 = leaky(p0), a1 = leaky(p1), a2 = leaky(p2);
    float o0 = leaky(lb[0] + a0 * lw[0] + a1 * lw[1] + a2 * lw[2]);
    float o1 = leaky(lb[1] + a0 * lw[3] + a1 * lw[4] + a2 * lw[5]);
    float o2 = leaky(lb[2] + a0 * lw[6] + a1 * lw[7] + a2 * lw[8]);
    out[v * 3 + 0] = o0;
    out[v * 3 + 1] = o1;
    out[v * 3 + 2] = o2;
}

// ---------------- launcher ----------------

extern "C" void kernel_launch(void* const* d_in, const int* in_sizes, int n_in,
                              void* d_out, int out_size, void* d_ws, size_t ws_size,
                              hipStream_t stream) {
    const float* x  = (const float*)d_in[0];
    const int*   ei = (const int*)d_in[1];
    const float* w0 = (const float*)d_in[2];
    const float* b0 = (const float*)d_in[3];
    const float* g0 = (const float*)d_in[4];
    const float* bb0 = (const float*)d_in[5];
    const float* lw0 = (const float*)d_in[6];
    const float* lb0 = (const float*)d_in[7];
    const float* w1 = (const float*)d_in[8];
    const float* b1 = (const float*)d_in[9];
    const float* g1 = (const float*)d_in[10];
    const float* bb1 = (const float*)d_in[11];
    const float* lw1 = (const float*)d_in[12];
    const float* lb1 = (const float*)d_in[13];
    const float* w2 = (const float*)d_in[14];
    const float* b2 = (const float*)d_in[15];
    const float* g2 = (const float*)d_in[16];
    const float* bb2 = (const float*)d_in[17];
    const float* lw2 = (const float*)d_in[18];
    const float* lb2 = (const float*)d_in[19];
    float* out = (float*)d_out;

    // workspace layout (16B-aligned first)
    char* w = (char*)d_ws;
    float* yraw = (float*)w;       w += (size_t)N_NODES * 64 * 4; // 20.48 MB
    float4* hs3 = (float4*)w;      w += (size_t)N_NODES * 16;     // 1.28 MB
    float4* y3raw = (float4*)w;    w += (size_t)N_NODES * 16;     // 1.28 MB
    int2* pairs = (int2*)w;        w += (size_t)NBKT * BKT_CAP * 8; // 10.56 MB
    bf16* hs = (bf16*)w;           w += (size_t)N_NODES * 64 * 2; // 10.24 MB
    int* deg = (int*)w;            w += (size_t)N_NODES * 4;
    float* dinv = (float*)w;       w += (size_t)N_NODES * 4;
    float* bnsum = (float*)w;      w += 384 * 4;
    int* tails = (int*)w;          w += 16 * 4;

    const int NB = (N_NODES + 255) / 256;  // 313

    // --- graph setup (no CSR: weights factorized out) ---
    k_zero<<<NB, 256, 0, stream>>>(deg, bnsum, tails);
    k_part<<<N_EDGES / EPB, 256, 0, stream>>>(ei, pairs, tails);
    k_deg_bkt<<<2048, 256, 0, stream>>>(pairs, tails, deg);
    k_dinv<<<NB, 256, 0, stream>>>(deg, dinv);

    // --- stage 0 ---
    k_h0y<<<(N_NODES * 64 + 255) / 256, 256, 0, stream>>>(x, w0, dinv, hs, yraw);
    k_agg_b<<<2048, 256, 0, stream>>>(hs, pairs, tails, yraw);
    k_bnstats<<<640, 256, 0, stream>>>(yraw, dinv, b0, bnsum);
    // reads yraw(stage0), writes hs(stage1) + yraw(stage1 init) in place
    k_post64<1, 0><<<1250, 128, 0, stream>>>(yraw, dinv, b0, bnsum, g0, bb0, lw0, lb0,
                                             w1, hs, yraw, nullptr, nullptr);

    // --- stage 1 ---
    k_agg_b<<<2048, 256, 0, stream>>>(hs, pairs, tails, yraw);
    k_bnstats<<<640, 256, 0, stream>>>(yraw, dinv, b1, bnsum + 128);
    k_post64<2, 1><<<1250, 128, 0, stream>>>(yraw, dinv, b1, bnsum + 128, g1, bb1, lw1, lb1,
                                             w2, nullptr, nullptr, hs3, y3raw);

    // --- stage 2 (C=3) ---
    k_agg3_b<<<2048, 256, 0, stream>>>(hs3, pairs, tails, (float*)y3raw);
    k_bnstats3<<<NB, 256, 0, stream>>>((const float*)y3raw, dinv, b2, bnsum + 256);
    k_post3<<<NB, 256, 0, stream>>>((const float*)y3raw, dinv, b2, bnsum + 256,
                                    g2, bb2, lw2, lb2, out);
}

// Round 10
// 493.520 us; speedup vs baseline: 2.1301x; 2.1301x over previous
//
#include <hip/hip_runtime.h>
#include <hip/hip_bf16.h>
#include <math.h>

#define N_NODES 80000
#define N_EDGES 1280000
#define CHUNK 128
#define N_CHUNKS (N_EDGES / CHUNK)  // 10000
#define NBKT 8
#define BKT_DIV 10000               // bucket = dst / 10000  -> 0..7
#define BKT_CAP 165000              // mean 160000, sigma ~374; huge margin
#define EPB 1280                    // edges per k_part block (grid 1000)

typedef __hip_bfloat16 bf16;

__device__ __forceinline__ float leaky(float x) { return x >= 0.f ? x : 0.01f * x; }

// ---------------- setup kernels ----------------

__global__ void k_zero(int* deg, float* bnsums, int* tails) {
    int i = blockIdx.x * blockDim.x + threadIdx.x;
    if (i < N_NODES) deg[i] = 0;
    if (i < 384) bnsums[i] = 0.f;
    if (i < NBKT) tails[i] = 0;
}

// pass 1: bin raw (src,dst) pairs by dst-range; block bulk-reserves regions.
// No deg atomics here (R7 lesson: random cross-XCD atomics = write storm).
__global__ void __launch_bounds__(256)
k_part(const int* __restrict__ ei, int2* __restrict__ pairs,
       int* __restrict__ tails) {
    __shared__ int cnt[NBKT], off[NBKT];
    int t = threadIdx.x;
    if (t < NBKT) cnt[t] = 0;
    __syncthreads();
    int base = blockIdx.x * EPB;
    int2 loc[5];
#pragma unroll
    for (int u = 0; u < 5; ++u) {
        int e = base + u * 256 + t;
        int s = ei[e], d = ei[N_EDGES + e];
        loc[u] = make_int2(s, d);
        atomicAdd(&cnt[d / BKT_DIV], 1);
    }
    __syncthreads();
    if (t < NBKT) off[t] = atomicAdd(&tails[t], cnt[t]);
    __syncthreads();
#pragma unroll
    for (int u = 0; u < 5; ++u) {
        int b = loc[u].y / BKT_DIV;
        int pos = atomicAdd(&off[b], 1);
        pairs[(size_t)b * BKT_CAP + pos] = loc[u];
    }
}

// deg counting, bucket-pinned (atomics confined to a 40 KB dst slice).
__global__ void __launch_bounds__(256)
k_deg_bkt(const int2* __restrict__ pairs, const int* __restrict__ tails,
          int* __restrict__ deg) {
    int bucket = blockIdx.x & 7;
    int jb = blockIdx.x >> 3;
    int nb = gridDim.x >> 3;
    int cnt = tails[bucket];
    const int2* lst = pairs + (size_t)bucket * BKT_CAP;
    for (int i = jb * 256 + threadIdx.x; i < cnt; i += nb * 256)
        atomicAdd(&deg[lst[i].y], 1);
}

__global__ void k_scanA(const int* __restrict__ deg, int* __restrict__ partial,
                        float* __restrict__ dinv) {
    __shared__ int s[256];
    int t = threadIdx.x;
    int i = blockIdx.x * 256 + t;
    int v = (i < N_NODES) ? deg[i] : 0;
    if (i < N_NODES) dinv[i] = rsqrtf((float)v + 2.0f);  // + self-loop weight 2
    s[t] = v;
    __syncthreads();
    for (int off = 128; off > 0; off >>= 1) {
        if (t < off) s[t] += s[t + off];
        __syncthreads();
    }
    if (t == 0) partial[blockIdx.x] = s[0];
}

__global__ void k_scanB(int* partial, int nb) {
    __shared__ int s[512];
    int t = threadIdx.x;
    int v = (t < nb) ? partial[t] : 0;
    s[t] = v;
    __syncthreads();
    for (int off = 1; off < 512; off <<= 1) {
        int x = (t >= off) ? s[t - off] : 0;
        __syncthreads();
        s[t] += x;
        __syncthreads();
    }
    if (t < nb) partial[t] = s[t] - v;  // exclusive
}

__global__ void k_scanC(const int* __restrict__ deg, const int* __restrict__ partial,
                        int* __restrict__ cursor) {
    __shared__ int s[256];
    int t = threadIdx.x;
    int i = blockIdx.x * 256 + t;
    int v = (i < N_NODES) ? deg[i] : 0;
    s[t] = v;
    __syncthreads();
    for (int off = 1; off < 256; off <<= 1) {
        int x = (t >= off) ? s[t - off] : 0;
        __syncthreads();
        s[t] += x;
        __syncthreads();
    }
    if (i < N_NODES) cursor[i] = partial[blockIdx.x] + s[t] - v;
}

// pass 2: per-bucket CSR scatter of thin (src,dst) records (8 B, no weight —
// factorized). After this, cursor[v] == row_end(v).
__global__ void __launch_bounds__(256)
k_scatter2(const int2* __restrict__ pairs, const int* __restrict__ tails,
           int* __restrict__ cursor, int2* __restrict__ ed2) {
    int bucket = blockIdx.x & 7;
    int jb = blockIdx.x >> 3;
    int nb = gridDim.x >> 3;
    int cnt = tails[bucket];
    const int2* lst = pairs + (size_t)bucket * BKT_CAP;
    for (int i = jb * 256 + threadIdx.x; i < cnt; i += nb * 256) {
        int2 pr = lst[i];
        int p = atomicAdd(&cursor[pr.y], 1);
        ed2[p] = pr;
    }
}

// h0 = x @ W0; hs = bf16(dinv*h0)  (pre-scaled gather rows)
__global__ void k_h0s(const float* __restrict__ x, const float* __restrict__ W0,
                      const float* __restrict__ dinv, bf16* __restrict__ hs) {
    int tid = blockIdx.x * blockDim.x + threadIdx.x;
    if (tid < N_NODES * 64) {
        int v = tid >> 6, c = tid & 63;
        float x0 = x[v * 3], x1 = x[v * 3 + 1], x2 = x[v * 3 + 2];
        float h = x0 * W0[c] + x1 * W0[64 + c] + x2 * W0[128 + c];
        hs[tid] = __float2bfloat16(dinv[v] * h);
    }
}

// ---------------- per-stage kernels ----------------

// segmented edge-stream aggregation over CSR-sorted thin records.
// Interior segments (fully inside the chunk, exclusively owned) -> plain store.
// Leading/trailing segments (may straddle chunks) -> atomicAdd (~2/chunk).
// yagg must be zero-initialized (memset).  R9 lesson: every wave-atomic is a
// full 256 B HBM line write — atomic count is the cost, so keep it ~20K.
__global__ void __launch_bounds__(256)
k_agg_seg(const bf16* __restrict__ hs, const int2* __restrict__ ed2,
          float* __restrict__ yagg) {
    int lane = threadIdx.x & 63;
    int wid = (blockIdx.x * blockDim.x + threadIdx.x) >> 6;
    if (wid >= N_CHUNKS) return;
    int e = wid * CHUNK;
    int2 c[8];
#pragma unroll
    for (int u = 0; u < 8; ++u) c[u] = ed2[e + u];
    float acc = 0.f;
    int cur = __builtin_amdgcn_readfirstlane(c[0].y);
    bool lead = true;  // current segment may extend into the previous chunk
    for (int b = 0; b < CHUNK / 8; ++b) {
        float pv[8];
#pragma unroll
        for (int u = 0; u < 8; ++u)
            pv[u] = __bfloat162float(hs[(size_t)c[u].x * 64 + lane]);
        int2 cn[8];
        if (b < CHUNK / 8 - 1) {
            int en = e + 8;
#pragma unroll
            for (int u = 0; u < 8; ++u) cn[u] = ed2[en + u];
        }
#pragma unroll
        for (int u = 0; u < 8; ++u) {
            int du = __builtin_amdgcn_readfirstlane(c[u].y);
            if (du != cur) {
                if (lead) {
                    atomicAdd(&yagg[(size_t)cur * 64 + lane], acc);
                    lead = false;
                } else {
                    yagg[(size_t)cur * 64 + lane] = acc;  // exclusive owner
                }
                acc = 0.f;
                cur = du;
            }
            acc += pv[u];
        }
        e += 8;
        if (b < CHUNK / 8 - 1) {
#pragma unroll
            for (int u = 0; u < 8; ++u) c[u] = cn[u];
        }
    }
    atomicAdd(&yagg[(size_t)cur * 64 + lane], acc);  // trailing: may straddle
}

// per-channel sum/sumsq of y_final = dinv[v]*(yagg + 2*hs_self) + bias[c]
__global__ void __launch_bounds__(256)
k_bnstats(const float* __restrict__ yagg, const bf16* __restrict__ hs,
          const float* __restrict__ dinv, const float* __restrict__ bias,
          float* __restrict__ bnsum) {
    int tid = blockIdx.x * blockDim.x + threadIdx.x;
    int stride = gridDim.x * blockDim.x;  // multiple of 64 -> lane == channel
    float bc = bias[tid & 63];
    float bs = 0.f, bss = 0.f;
    for (size_t i = tid; i < (size_t)N_NODES * 64; i += stride) {
        float comb = yagg[i] + 2.f * __bfloat162float(hs[i]);
        float yf = dinv[i >> 6] * comb + bc;
        bs += yf;
        bss += yf * yf;
    }
    __shared__ float s1[256], s2[256];
    s1[threadIdx.x] = bs;
    s2[threadIdx.x] = bss;
    __syncthreads();
    if (threadIdx.x < 64) {
        float t1 = s1[threadIdx.x] + s1[threadIdx.x + 64] + s1[threadIdx.x + 128] + s1[threadIdx.x + 192];
        float t2 = s2[threadIdx.x] + s2[threadIdx.x + 64] + s2[threadIdx.x + 128] + s2[threadIdx.x + 192];
        atomicAdd(&bnsum[threadIdx.x], t1);
        atomicAdd(&bnsum[64 + threadIdx.x], t2);
    }
}

// BN + maxpool + leaky + (a@lw.T+lb) + leaky + second matmul, register-tiled.
// Phase 1 input: y_final = dinv*(yagg + 2*hs_self) + bias (bias folded into BN shift).
// MODE 0: phase3 = o @ Wn (64x64) -> hs_next = bf16(dinv*hn).
// MODE 1: phase3 = o @ Wn (64x3)  -> hs3 = float4(dinv*h3).
template <int P, int MODE>
__global__ void __launch_bounds__(128)
k_post64(const float* __restrict__ yagg, const bf16* __restrict__ hs,
         const float* __restrict__ dinv, const float* __restrict__ bias,
         const float* __restrict__ bnsum,
         const float* __restrict__ g, const float* __restrict__ bb,
         const float* __restrict__ lw, const float* __restrict__ lb,
         const float* __restrict__ Wn, bf16* __restrict__ hsout,
         float4* __restrict__ hs3) {
    __shared__ float s_aT[2][64 * 36];  // per-wave activation tile (transposed), reused as oT
    __shared__ float s_lwT[64 * 64];    // lw transposed: [k][c]
    __shared__ float s_Wn[MODE == 0 ? 64 * 64 : 64 * 3];
    int t = threadIdx.x;
    int w = t >> 6, lane = t & 63;
    for (int k0 = t; k0 < 4096; k0 += 128) {
        int kk = k0 >> 6, cc = k0 & 63;
        s_lwT[kk * 64 + cc] = lw[cc * 64 + kk];
        if (MODE == 0) s_Wn[k0] = Wn[k0];
    }
    if (MODE == 1) {
        for (int i = t; i < 64 * 3; i += 128) s_Wn[i] = Wn[i];
    }
    float inv_n = 1.0f / (float)N_NODES;
    float mean = bnsum[lane] * inv_n;
    float var = fmaxf(bnsum[64 + lane] * inv_n - mean * mean, 0.f);
    float sc = g[lane] * rsqrtf(var + 1e-5f);
    float sh = bb[lane] - mean * sc;
    float shb = fmaf(sc, bias[lane], sh);  // folds GCN bias into BN shift
    int c0 = (lane >> 3) * 8, n0 = (lane & 7) * 4;
    float lbv[8];
#pragma unroll
    for (int i = 0; i < 8; ++i) lbv[i] = lb[c0 + i];
    float* aT = s_aT[w];

    for (int tile = blockIdx.x; tile < N_NODES / 64; tile += gridDim.x) {
        int nbase = tile * 64 + w * 32;
        __syncthreads();  // also covers initial weight-fill -> first use
#pragma unroll 4
        for (int i = 0; i < 32; ++i) {
            size_t idx = (size_t)(nbase + i) * 64 + lane;
            float comb = yagg[idx] + 2.f * __bfloat162float(hs[idx]);
            float z = fmaf(sc * dinv[nbase + i], comb, shb);
            float m = z;
#pragma unroll
            for (int d = 1; d <= P; ++d) {
                float up = __shfl(z, lane + d);
                float dn = __shfl(z, lane - d);
                m = fmaxf(m, (lane + d < 64) ? up : -INFINITY);
                m = fmaxf(m, (lane - d >= 0) ? dn : -INFINITY);
            }
            aT[lane * 36 + i] = leaky(m);
        }
        __syncthreads();
        // phase 2: o = leaky(a @ lw.T + lb)
        float acc[4][8];
#pragma unroll
        for (int nn = 0; nn < 4; ++nn)
#pragma unroll
            for (int i = 0; i < 8; ++i) acc[nn][i] = lbv[i];
#pragma unroll 8
        for (int k = 0; k < 64; ++k) {
            float4 av = *(const float4*)&aT[k * 36 + n0];
            float4 w0 = *(const float4*)&s_lwT[k * 64 + c0];
            float4 w1 = *(const float4*)&s_lwT[k * 64 + c0 + 4];
            float a4[4] = {av.x, av.y, av.z, av.w};
            float wv[8] = {w0.x, w0.y, w0.z, w0.w, w1.x, w1.y, w1.z, w1.w};
#pragma unroll
            for (int nn = 0; nn < 4; ++nn)
#pragma unroll
                for (int i = 0; i < 8; ++i) acc[nn][i] = fmaf(a4[nn], wv[i], acc[nn][i]);
        }
#pragma unroll
        for (int nn = 0; nn < 4; ++nn)
#pragma unroll
            for (int i = 0; i < 8; ++i) acc[nn][i] = leaky(acc[nn][i]);

        // write oT (aliases aT; same-wave LDS program order is safe)
#pragma unroll
        for (int i = 0; i < 8; ++i) {
            float4 ov = make_float4(acc[0][i], acc[1][i], acc[2][i], acc[3][i]);
            *(float4*)&aT[(c0 + i) * 36 + n0] = ov;
        }
        if (MODE == 0) {
            float acc2[4][8];
#pragma unroll
            for (int nn = 0; nn < 4; ++nn)
#pragma unroll
                for (int i = 0; i < 8; ++i) acc2[nn][i] = 0.f;
#pragma unroll 8
            for (int k = 0; k < 64; ++k) {
                float4 av = *(const float4*)&aT[k * 36 + n0];
                float4 w0 = *(const float4*)&s_Wn[k * 64 + c0];
                float4 w1 = *(const float4*)&s_Wn[k * 64 + c0 + 4];
                float a4[4] = {av.x, av.y, av.z, av.w};
                float wv[8] = {w0.x, w0.y, w0.z, w0.w, w1.x, w1.y, w1.z, w1.w};
#pragma unroll
                for (int nn = 0; nn < 4; ++nn)
#pragma unroll
                    for (int i = 0; i < 8; ++i) acc2[nn][i] = fmaf(a4[nn], wv[i], acc2[nn][i]);
            }
#pragma unroll
            for (int nn = 0; nn < 4; ++nn) {
                int node = nbase + n0 + nn;
                float dv = dinv[node];
                bf16 pk[8];
#pragma unroll
                for (int i = 0; i < 8; ++i) pk[i] = __float2bfloat16(dv * acc2[nn][i]);
                *(uint4*)&hsout[(size_t)node * 64 + c0] = *(uint4*)pk;
            }
        } else {
            // proj fused: h3 = o @ w2 (64x3); 8 lanes duplicate, c0==0 writes
            float acc3[4][3];
#pragma unroll
            for (int nn = 0; nn < 4; ++nn)
#pragma unroll
                for (int j = 0; j < 3; ++j) acc3[nn][j] = 0.f;
#pragma unroll 8
            for (int k = 0; k < 64; ++k) {
                float4 av = *(const float4*)&aT[k * 36 + n0];
                float a4[4] = {av.x, av.y, av.z, av.w};
                float w0 = s_Wn[k * 3 + 0], w1 = s_Wn[k * 3 + 1], w2v = s_Wn[k * 3 + 2];
#pragma unroll
                for (int nn = 0; nn < 4; ++nn) {
                    acc3[nn][0] = fmaf(a4[nn], w0, acc3[nn][0]);
                    acc3[nn][1] = fmaf(a4[nn], w1, acc3[nn][1]);
                    acc3[nn][2] = fmaf(a4[nn], w2v, acc3[nn][2]);
                }
            }
            if (c0 == 0) {
#pragma unroll
                for (int nn = 0; nn < 4; ++nn) {
                    int node = nbase + n0 + nn;
                    float dv = dinv[node];
                    hs3[node] = make_float4(dv * acc3[nn][0], dv * acc3[nn][1],
                                            dv * acc3[nn][2], 0.f);
                }
            }
        }
    }
}

// stage-2 aggregation: thread-per-node over CSR (cursor), plain stores, no atomics.
__global__ void __launch_bounds__(256)
k_agg3(const float4* __restrict__ hs3, const int* __restrict__ cursor,
       const int2* __restrict__ ed2, float4* __restrict__ y3agg) {
    int v = blockIdx.x * blockDim.x + threadIdx.x;
    if (v >= N_NODES) return;
    int end = cursor[v];
    int start = (v == 0) ? 0 : cursor[v - 1];
    float a0 = 0.f, a1 = 0.f, a2 = 0.f;
    int e = start;
    for (; e + 4 <= end; e += 4) {
        int2 c[4];
#pragma unroll
        for (int u = 0; u < 4; ++u) c[u] = ed2[e + u];
#pragma unroll
        for (int u = 0; u < 4; ++u) {
            float4 h = hs3[c[u].x];
            a0 += h.x; a1 += h.y; a2 += h.z;
        }
    }
    for (; e < end; ++e) {
        float4 h = hs3[ed2[e].x];
        a0 += h.x; a1 += h.y; a2 += h.z;
    }
    y3agg[v] = make_float4(a0, a1, a2, 0.f);
}

// stage-2 BN stats over y_final = dinv*(y3agg + 2*hs3) + b2
__global__ void __launch_bounds__(256)
k_bnstats3(const float4* __restrict__ y3agg, const float4* __restrict__ hs3,
           const float* __restrict__ dinv, const float* __restrict__ b2,
           float* __restrict__ bnsum) {
    int v = blockIdx.x * blockDim.x + threadIdx.x;
    float y0 = 0.f, y1 = 0.f, y2 = 0.f;
    if (v < N_NODES) {
        float dv = dinv[v];
        float4 ya = y3agg[v];
        float4 h = hs3[v];
        y0 = dv * (ya.x + 2.f * h.x) + b2[0];
        y1 = dv * (ya.y + 2.f * h.y) + b2[1];
        y2 = dv * (ya.z + 2.f * h.z) + b2[2];
    }
    __shared__ float sm[256];
    float vals[6] = {y0, y1, y2, y0 * y0, y1 * y1, y2 * y2};
    for (int c = 0; c < 6; ++c) {
        sm[threadIdx.x] = (v < N_NODES) ? vals[c] : 0.f;
        __syncthreads();
        for (int off = 128; off > 0; off >>= 1) {
            if (threadIdx.x < off) sm[threadIdx.x] += sm[threadIdx.x + off];
            __syncthreads();
        }
        if (threadIdx.x == 0) atomicAdd(&bnsum[c], sm[0]);
        __syncthreads();
    }
}

// final stage post: BN + pool(3,1) + leaky + 3x3 linear + leaky
__global__ void k_post3(const float4* __restrict__ y3agg, const float4* __restrict__ hs3,
                        const float* __restrict__ dinv, const float* __restrict__ b2,
                        const float* __restrict__ bnsum,
                        const float* __restrict__ g, const float* __restrict__ bb,
                        const float* __restrict__ lw, const float* __restrict__ lb,
                        float* __restrict__ out) {
    int v = blockIdx.x * blockDim.x + threadIdx.x;
    if (v >= N_NODES) return;
    float inv_n = 1.0f / (float)N_NODES;
    float sc[3], sh[3];
#pragma unroll
    for (int c = 0; c < 3; ++c) {
        float mean = bnsum[c] * inv_n;
        float var = fmaxf(bnsum[3 + c] * inv_n - mean * mean, 0.f);
        sc[c] = g[c] * rsqrtf(var + 1e-5f);
        sh[c] = bb[c] - mean * sc[c];
    }
    float dv = dinv[v];
    float4 ya = y3agg[v];
    float4 h = hs3[v];
    float z0 = fmaf(dv * (ya.x + 2.f * h.x) + b2[0], sc[0], sh[0]);
    float z1 = fmaf(dv * (ya.y + 2.f * h.y) + b2[1], sc[1], sh[1]);
    float z2 = fmaf(dv * (ya.z + 2.f * h.z) + b2[2], sc[2], sh[2]);
    float p0 = fmaxf(z0, z1);
    float p1 = fmaxf(p0, z2);
    float p2 = fmaxf(z1, z2);
    float a0 = leaky(p0), a1 = leaky(p1), a2 = leaky(p2);
    float o0 = leaky(lb[0] + a0 * lw[0] + a1 * lw[1] + a2 * lw[2]);
    float o1 = leaky(lb[1] + a0 * lw[3] + a1 * lw[4] + a2 * lw[5]);
    float o2 = leaky(lb[2] + a0 * lw[6] + a1 * lw[7] + a2 * lw[8]);
    out[v * 3 + 0] = o0;
    out[v * 3 + 1] = o1;
    out[v * 3 + 2] = o2;
}

// ---------------- launcher ----------------

extern "C" void kernel_launch(void* const* d_in, const int* in_sizes, int n_in,
                              void* d_out, int out_size, void* d_ws, size_t ws_size,
                              hipStream_t stream) {
    const float* x  = (const float*)d_in[0];
    const int*   ei = (const int*)d_in[1];
    const float* w0 = (const float*)d_in[2];
    const float* b0 = (const float*)d_in[3];
    const float* g0 = (const float*)d_in[4];
    const float* bb0 = (const float*)d_in[5];
    const float* lw0 = (const float*)d_in[6];
    const float* lb0 = (const float*)d_in[7];
    const float* w1 = (const float*)d_in[8];
    const float* b1 = (const float*)d_in[9];
    const float* g1 = (const float*)d_in[10];
    const float* bb1 = (const float*)d_in[11];
    const float* lw1 = (const float*)d_in[12];
    const float* lb1 = (const float*)d_in[13];
    const float* w2 = (const float*)d_in[14];
    const float* b2 = (const float*)d_in[15];
    const float* g2 = (const float*)d_in[16];
    const float* bb2 = (const float*)d_in[17];
    const float* lw2 = (const float*)d_in[18];
    const float* lb2 = (const float*)d_in[19];
    float* out = (float*)d_out;

    // workspace layout (16B-aligned first)
    char* w = (char*)d_ws;
    float* yagg = (float*)w;       w += (size_t)N_NODES * 64 * 4;   // 20.48 MB
    int2* ed2 = (int2*)w;          w += (size_t)N_EDGES * 8;        // 10.24 MB
    bf16* hs = (bf16*)w;           w += (size_t)N_NODES * 64 * 2;   // 10.24 MB
    float4* hs3 = (float4*)w;      w += (size_t)N_NODES * 16;       // 1.28 MB
    float4* y3agg = (float4*)w;    w += (size_t)N_NODES * 16;       // 1.28 MB
    int* deg = (int*)w;            w += (size_t)N_NODES * 4;
    float* dinv = (float*)w;       w += (size_t)N_NODES * 4;
    int* cursor = (int*)w;         w += (size_t)N_NODES * 4;
    int* partial = (int*)w;        w += 512 * 4;
    float* bnsum = (float*)w;      w += 384 * 4;
    int* tails = (int*)w;          w += 16 * 4;
    // pairs overlays yagg (dead until first memset); 10.56 MB <= 20.48 MB
    int2* pairs = (int2*)yagg;

    const int NB = (N_NODES + 255) / 256;  // 313

    // --- graph/CSR setup ---
    k_zero<<<NB, 256, 0, stream>>>(deg, bnsum, tails);
    k_part<<<N_EDGES / EPB, 256, 0, stream>>>(ei, pairs, tails);
    k_deg_bkt<<<2048, 256, 0, stream>>>(pairs, tails, deg);
    k_scanA<<<NB, 256, 0, stream>>>(deg, partial, dinv);
    k_scanB<<<1, 512, 0, stream>>>(partial, NB);
    k_scanC<<<NB, 256, 0, stream>>>(deg, partial, cursor);
    k_scatter2<<<2048, 256, 0, stream>>>(pairs, tails, cursor, ed2);

    // --- stage 0 ---
    k_h0s<<<(N_NODES * 64 + 255) / 256, 256, 0, stream>>>(x, w0, dinv, hs);
    hipMemsetAsync(yagg, 0, (size_t)N_NODES * 64 * 4, stream);  // pairs dead now
    k_agg_seg<<<2500, 256, 0, stream>>>(hs, ed2, yagg);
    k_bnstats<<<640, 256, 0, stream>>>(yagg, hs, dinv, b0, bnsum);
    k_post64<1, 0><<<1250, 128, 0, stream>>>(yagg, hs, dinv, b0, bnsum, g0, bb0,
                                             lw0, lb0, w1, hs, nullptr);

    // --- stage 1 ---
    hipMemsetAsync(yagg, 0, (size_t)N_NODES * 64 * 4, stream);
    k_agg_seg<<<2500, 256, 0, stream>>>(hs, ed2, yagg);
    k_bnstats<<<640, 256, 0, stream>>>(yagg, hs, dinv, b1, bnsum + 128);
    k_post64<2, 1><<<1250, 128, 0, stream>>>(yagg, hs, dinv, b1, bnsum + 128, g1, bb1,
                                             lw1, lb1, w2, nullptr, hs3);

    // --- stage 2 (C=3) ---
    k_agg3<<<NB, 256, 0, stream>>>(hs3, cursor, ed2, y3agg);
    k_bnstats3<<<NB, 256, 0, stream>>>(y3agg, hs3, dinv, b2, bnsum + 256);
    k_post3<<<NB, 256, 0, stream>>>(y3agg, hs3, dinv, b2, bnsum + 256,
                                    g2, bb2, lw2, lb2, out);
}